// Round 7
// baseline (206.977 us; speedup 1.0000x reference)
//
#include <hip/hip_runtime.h>
#include <hip/hip_bf16.h>

#define BB 16
#define CC 512
#define NN 1024
#define GG 8
#define HHH 8
#define DH 64

typedef __bf16 bf16x8 __attribute__((ext_vector_type(8)));
typedef float f32x4 __attribute__((ext_vector_type(4)));
typedef float f32x16 __attribute__((ext_vector_type(16)));
typedef unsigned int u32x4 __attribute__((ext_vector_type(4)));

// scale * log2(e), folded into Q at projection time so S' = q'.k is the exp2 argument
#define QSCALE 0.18033688011116027f

__device__ __forceinline__ unsigned short bfb(float f) {
    __hip_bfloat16 h = __float2bfloat16(f);
    return __builtin_bit_cast(unsigned short, h);
}

__device__ __forceinline__ bf16x8 ldb8(const void* p) {
    return *reinterpret_cast<const bf16x8*>(p);
}

__device__ __forceinline__ unsigned int cvtpk(float lo, float hi) {
    unsigned int r;
    asm("v_cvt_pk_bf16_f32 %0, %1, %2" : "=v"(r) : "v"(lo), "v"(hi));
    return r;
}

typedef const __attribute__((address_space(1))) unsigned int* gas_ptr;
typedef __attribute__((address_space(3))) unsigned int* las_ptr;
__device__ __forceinline__ void gload_lds16(const void* g, void* l) {
    __builtin_amdgcn_global_load_lds((gas_ptr)g, (las_ptr)l, 16, 0, 0);
}

// ---------------- kernel 0: fp32 -> bf16 weight conversion ----------------
__global__ __launch_bounds__(256) void wconv_kernel(
    const float4* __restrict__ wq, const float4* __restrict__ wk,
    const float4* __restrict__ wv, const float4* __restrict__ wo,
    ushort4* __restrict__ oq, ushort4* __restrict__ ok2,
    ushort4* __restrict__ ov, ushort4* __restrict__ oo) {
    int i = blockIdx.x * 256 + threadIdx.x;  // over C*C/4 = 65536
    float4 a;
    ushort4 r;
    a = wq[i]; r.x = bfb(a.x); r.y = bfb(a.y); r.z = bfb(a.z); r.w = bfb(a.w); oq[i] = r;
    a = wk[i]; r.x = bfb(a.x); r.y = bfb(a.y); r.z = bfb(a.z); r.w = bfb(a.w); ok2[i] = r;
    a = wv[i]; r.x = bfb(a.x); r.y = bfb(a.y); r.z = bfb(a.z); r.w = bfb(a.w); ov[i] = r;
    a = wo[i]; r.x = bfb(a.x); r.y = bfb(a.y); r.z = bfb(a.z); r.w = bfb(a.w); oo[i] = r;
}

// ---------------- kernel 1: GroupNorm -> xnT [B][N][C] bf16 ----------------
__global__ __launch_bounds__(256) void gn_kernel(
    const float* __restrict__ x, const float* __restrict__ gamma,
    const float* __restrict__ beta, unsigned short* __restrict__ xnT) {
    int b = blockIdx.x >> 3, g = blockIdx.x & 7;
    const float* xg = x + ((size_t)b * CC + g * 64) * NN;
    int t = threadIdx.x;

    float s = 0.f, s2 = 0.f;
    for (int i = 0; i < 64; ++i) {
        float4 v = reinterpret_cast<const float4*>(xg)[t + i * 256];
        s += v.x + v.y + v.z + v.w;
        s2 += v.x * v.x + v.y * v.y + v.z * v.z + v.w * v.w;
    }
    #pragma unroll
    for (int m = 1; m < 64; m <<= 1) {
        s += __shfl_xor(s, m);
        s2 += __shfl_xor(s2, m);
    }
    __shared__ float red[2][4];
    int wid = t >> 6;
    if ((t & 63) == 0) { red[0][wid] = s; red[1][wid] = s2; }
    __syncthreads();
    s = red[0][0] + red[0][1] + red[0][2] + red[0][3];
    s2 = red[1][0] + red[1][1] + red[1][2] + red[1][3];
    float mean = s * (1.f / 65536.f);
    float var = s2 * (1.f / 65536.f) - mean * mean;
    float rstd = rsqrtf(var + 1e-5f);

    __shared__ unsigned short tile[64][68];
    for (int nt = 0; nt < 16; ++nt) {
        __syncthreads();
        #pragma unroll
        for (int p = 0; p < 4; ++p) {
            int cc = p * 16 + (t >> 4);
            int nn = (t & 15) * 4;
            float4 v = *reinterpret_cast<const float4*>(&xg[(size_t)cc * NN + nt * 64 + nn]);
            float ga = gamma[g * 64 + cc], be = beta[g * 64 + cc];
            float aa = rstd * ga;
            float c0 = be - mean * aa;
            ushort4 pk;
            pk.x = bfb(v.x * aa + c0);
            pk.y = bfb(v.y * aa + c0);
            pk.z = bfb(v.z * aa + c0);
            pk.w = bfb(v.w * aa + c0);
            *reinterpret_cast<ushort4*>(&tile[cc][nn]) = pk;
        }
        __syncthreads();
        #pragma unroll
        for (int p = 0; p < 16; ++p) {
            int nn = p * 4 + (t >> 6);
            int cc = t & 63;
            xnT[((size_t)b * NN + nt * 64 + nn) * CC + g * 64 + cc] = tile[cc][nn];
        }
    }
}

// ---------------- kernel 2: fused QKV projections, LDS-staged GEMM ----------------
// Q output pre-scaled by QSCALE so attention's exp2 argument is the raw QK dot.
__global__ __launch_bounds__(256, 2) void qkv2_kernel(
    const unsigned short* __restrict__ wqb, const unsigned short* __restrict__ wkb,
    const unsigned short* __restrict__ wvb,
    const float* __restrict__ bq, const float* __restrict__ bk, const float* __restrict__ bv,
    const unsigned short* __restrict__ xnT,
    unsigned short* __restrict__ qt, unsigned short* __restrict__ kt,
    unsigned short* __restrict__ vv) {
    int wg = blockIdx.x;
    int xcd = wg & 7, local = wg >> 3;       // local 0..191
    int mloc = local / 12;                    // 0..15
    int rem = local - mloc * 12;
    int n_tile = rem / 3;                     // 0..3
    int p = rem - n_tile * 3;                 // 0..2
    int m_tile = xcd * 16 + mloc;             // 0..127

    const unsigned short* w = (p == 0) ? wqb : (p == 1) ? wkb : wvb;
    const float* bias = (p == 0) ? bq : (p == 1) ? bk : bv;
    int row0 = m_tile * 128;                  // global (b,n) row
    int o0t = n_tile * 128;                   // output channel base

    __shared__ __align__(16) char As[2][16384];
    __shared__ __align__(16) char Bs[2][16384];

    int t = threadIdx.x;
    int lane = t & 63, wid = t >> 6;
    int Rl = lane >> 3;                       // 0..7 row within 8-row group
    int csw = ((lane & 7) ^ Rl) << 4;         // pre-swizzled source chunk (bytes)

    const char* Ag = (const char*)xnT + (size_t)row0 * 1024;
    const char* Bg = (const char*)w + (size_t)o0t * 1024;

    #pragma unroll
    for (int j = 0; j < 4; ++j) {             // stage k0=0 into buf 0
        int ii = wid * 4 + j;
        size_t ro = (size_t)(ii * 8 + Rl) * 1024 + csw;
        gload_lds16(Ag + ro, &As[0][ii * 1024]);
        gload_lds16(Bg + ro, &Bs[0][ii * 1024]);
    }
    __syncthreads();

    int wr = wid & 1, wc = wid >> 1;          // wave -> 64x64 quadrant
    int lr = lane & 15, lg = lane >> 4;
    f32x4 acc[4][4] = {};

    for (int ks = 0; ks < 8; ++ks) {
        int cb_ = ks & 1;
        if (ks < 7) {
            int k0 = (ks + 1) * 64;
            #pragma unroll
            for (int j = 0; j < 4; ++j) {
                int ii = wid * 4 + j;
                size_t ro = (size_t)(ii * 8 + Rl) * 1024 + k0 * 2 + csw;
                gload_lds16(Ag + ro, &As[cb_ ^ 1][ii * 1024]);
                gload_lds16(Bg + ro, &Bs[cb_ ^ 1][ii * 1024]);
            }
        }
        const char* al = As[cb_];
        const char* bl = Bs[cb_];
        #pragma unroll
        for (int kk = 0; kk < 2; ++kk) {
            bf16x8 wf[4], xf[4];
            #pragma unroll
            for (int r = 0; r < 4; ++r) {
                int row = wc * 64 + r * 16 + lr;
                wf[r] = ldb8(bl + row * 128 + (((kk * 4 + lg) ^ (row & 7)) << 4));
            }
            #pragma unroll
            for (int c = 0; c < 4; ++c) {
                int row = wr * 64 + c * 16 + lr;
                xf[c] = ldb8(al + row * 128 + (((kk * 4 + lg) ^ (row & 7)) << 4));
            }
            __builtin_amdgcn_s_setprio(1);
            #pragma unroll
            for (int r = 0; r < 4; ++r)
                #pragma unroll
                for (int c = 0; c < 4; ++c)
                    acc[r][c] = __builtin_amdgcn_mfma_f32_16x16x32_bf16(wf[r], xf[c], acc[r][c], 0, 0, 0);
            __builtin_amdgcn_s_setprio(0);
        }
        __syncthreads();
    }

    // epilogue
    #pragma unroll
    for (int r = 0; r < 4; ++r) {
        int o0 = o0t + wc * 64 + r * 16 + lg * 4;
        #pragma unroll
        for (int c = 0; c < 4; ++c) {
            int grow = row0 + wr * 64 + c * 16 + lr;
            int b = grow >> 10, n = grow & 1023;
            float v0 = acc[r][c][0] + bias[o0 + 0];
            float v1 = acc[r][c][1] + bias[o0 + 1];
            float v2 = acc[r][c][2] + bias[o0 + 2];
            float v3 = acc[r][c][3] + bias[o0 + 3];
            if (p < 2) {
                if (p == 0) { v0 *= QSCALE; v1 *= QSCALE; v2 *= QSCALE; v3 *= QSCALE; }
                unsigned short* outp = (p == 0) ? qt : kt;
                int h = o0 >> 6, d = o0 & 63;
                ushort4 pk;
                pk.x = bfb(v0); pk.y = bfb(v1); pk.z = bfb(v2); pk.w = bfb(v3);
                *reinterpret_cast<ushort4*>(outp + ((size_t)(b * HHH + h) * NN + n) * DH + d) = pk;
            } else {
                vv[((size_t)b * CC + o0 + 0) * NN + n] = bfb(v0);
                vv[((size_t)b * CC + o0 + 1) * NN + n] = bfb(v1);
                vv[((size_t)b * CC + o0 + 2) * NN + n] = bfb(v2);
                vv[((size_t)b * CC + o0 + 3) * NN + n] = bfb(v3);
            }
        }
    }
}

// ---------------- kernel 3: flash attention, S-pipelined ring-3 (attn7) ----------------
// Max-free softmax (QSCALE folded into Q). Per iter: QK for tile t+1 (matrix pipe)
// overlaps exp2/pack of tile t (trans/VALU pipes); PV(t) closes. K/V in a 3-buffer
// shared LDS ring: STAGE(t+2) targets a buffer nobody reads this iter, so the only
// per-iter wait drains loads issued a full iteration ago. 48KB LDS -> 3 blocks/CU.
__global__ __launch_bounds__(256, 3) void attn7_kernel(
    const unsigned short* __restrict__ qt, const unsigned short* __restrict__ kt,
    const unsigned short* __restrict__ vv, unsigned short* __restrict__ aoT) {
    int wg = blockIdx.x;
    int bh = ((wg >> 6) << 3) + (wg & 7);  // all 8 qtiles of a head share an XCD
    int qt8 = (wg >> 3) & 7;
    int b = bh >> 3, h = bh & 7;
    int lane = threadIdx.x & 63, wid = threadIdx.x >> 6;
    int nl = lane & 31, hi = lane >> 5;
    int n = qt8 * 128 + wid * 32 + nl;

    const unsigned short* Qb = qt + (size_t)bh * NN * DH;
    const unsigned short* Kb = kt + (size_t)bh * NN * DH;
    const unsigned short* Vb = vv + ((size_t)b * CC + h * DH) * NN;

    __shared__ __align__(16) char smem[3][16384];  // ring: [K 8KB | V 8KB]

    const unsigned short* Qp = Qb + (size_t)n * DH + hi * 8;
    bf16x8 qf[4];
    qf[0] = ldb8(Qp);
    qf[1] = ldb8(Qp + 16);
    qf[2] = ldb8(Qp + 32);
    qf[3] = ldb8(Qp + 48);

    int Rl = lane >> 3;                    // 0..7
    int cs16 = 16 * ((lane & 7) ^ Rl);     // pre-swizzled col bytes (T2, rule #21)
    const char* Kc = (const char*)Kb;      // key rows, 128B stride
    const char* Vc = (const char*)Vb;      // d rows, 2048B stride

    #define STAGE(tt, buf)                                                        \
        {                                                                         \
            int m0_ = (tt) * 64;                                                  \
            _Pragma("unroll")                                                     \
            for (int j = 0; j < 2; ++j) {                                         \
                int ii = 2 * wid + j;                                             \
                int R = ii * 8 + Rl;                                              \
                gload_lds16(Kc + (size_t)(m0_ + R) * 128 + cs16,                  \
                            &smem[buf][ii * 1024]);                               \
                gload_lds16(Vc + (size_t)R * 2048 + (size_t)m0_ * 2 + cs16,       \
                            &smem[buf][8192 + ii * 1024]);                        \
            }                                                                     \
        }

    int swz = (nl & 7) << 4;
    int rowA = nl * 128, rowB = (nl + 32) * 128;

    // QK for tile TT from ring slot TT%3 into SN0/SN1 (zero-init by caller)
    #define QK_READ(SN0, SN1, TT)                                                 \
        {                                                                         \
            const char* kl_ = &smem[(TT) % 3][0];                                 \
            bf16x8 k0_ = ldb8(kl_ + rowA + ((hi * 16 +  0) ^ swz));               \
            bf16x8 k1_ = ldb8(kl_ + rowA + ((hi * 16 + 32) ^ swz));               \
            bf16x8 k2_ = ldb8(kl_ + rowA + ((hi * 16 + 64) ^ swz));               \
            bf16x8 k3_ = ldb8(kl_ + rowA + ((hi * 16 + 96) ^ swz));               \
            bf16x8 l0_ = ldb8(kl_ + rowB + ((hi * 16 +  0) ^ swz));               \
            bf16x8 l1_ = ldb8(kl_ + rowB + ((hi * 16 + 32) ^ swz));               \
            bf16x8 l2_ = ldb8(kl_ + rowB + ((hi * 16 + 64) ^ swz));               \
            bf16x8 l3_ = ldb8(kl_ + rowB + ((hi * 16 + 96) ^ swz));               \
            __builtin_amdgcn_s_setprio(1);                                        \
            SN0 = __builtin_amdgcn_mfma_f32_32x32x16_bf16(k0_, qf[0], SN0, 0, 0, 0); \
            SN1 = __builtin_amdgcn_mfma_f32_32x32x16_bf16(l0_, qf[0], SN1, 0, 0, 0); \
            SN0 = __builtin_amdgcn_mfma_f32_32x32x16_bf16(k1_, qf[1], SN0, 0, 0, 0); \
            SN1 = __builtin_amdgcn_mfma_f32_32x32x16_bf16(l1_, qf[1], SN1, 0, 0, 0); \
            SN0 = __builtin_amdgcn_mfma_f32_32x32x16_bf16(k2_, qf[2], SN0, 0, 0, 0); \
            SN1 = __builtin_amdgcn_mfma_f32_32x32x16_bf16(l2_, qf[2], SN1, 0, 0, 0); \
            SN0 = __builtin_amdgcn_mfma_f32_32x32x16_bf16(k3_, qf[3], SN0, 0, 0, 0); \
            SN1 = __builtin_amdgcn_mfma_f32_32x32x16_bf16(l3_, qf[3], SN1, 0, 0, 0); \
            __builtin_amdgcn_s_setprio(0);                                        \
        }

    // full per-tile body: consume SC (tile T), produce SN (tile T+1)
    #define BODY(SC0, SC1, SN0, SN1, T)                                           \
    {                                                                             \
        asm volatile("s_waitcnt lgkmcnt(0)" ::: "memory");                        \
        asm volatile("s_waitcnt vmcnt(0)" ::: "memory");                          \
        __builtin_amdgcn_s_barrier();                                             \
        if ((T) < 14) STAGE((T) + 2, ((T) + 2) % 3);                              \
        if ((T) < 15) {                                                           \
            SN0 = (f32x16){};                                                     \
            SN1 = (f32x16){};                                                     \
            QK_READ(SN0, SN1, (T) + 1);                                           \
        }                                                                         \
        _Pragma("unroll")                                                         \
        for (int e = 0; e < 16; ++e) SC0[e] = __builtin_amdgcn_exp2f(SC0[e]);     \
        _Pragma("unroll")                                                         \
        for (int e = 0; e < 16; ++e) SC1[e] = __builtin_amdgcn_exp2f(SC1[e]);     \
        _Pragma("unroll")                                                         \
        for (int e = 0; e < 4; ++e) {                                             \
            tsa[e] += (SC0[e] + SC0[e + 4]) + (SC0[e + 8] + SC0[e + 12]);         \
            tsb[e] += (SC1[e] + SC1[e + 4]) + (SC1[e + 8] + SC1[e + 12]);         \
        }                                                                         \
        unsigned pA = cvtpk(SC0[0], SC0[1]), pB = cvtpk(SC0[4], SC0[5]);          \
        asm("v_permlane32_swap_b32 %0, %1" : "+v"(pA), "+v"(pB));                 \
        unsigned pC = cvtpk(SC0[2], SC0[3]), pD = cvtpk(SC0[6], SC0[7]);          \
        asm("v_permlane32_swap_b32 %0, %1" : "+v"(pC), "+v"(pD));                 \
        unsigned pE = cvtpk(SC0[8], SC0[9]), pF = cvtpk(SC0[12], SC0[13]);        \
        asm("v_permlane32_swap_b32 %0, %1" : "+v"(pE), "+v"(pF));                 \
        unsigned pG = cvtpk(SC0[10], SC0[11]), pH = cvtpk(SC0[14], SC0[15]);      \
        asm("v_permlane32_swap_b32 %0, %1" : "+v"(pG), "+v"(pH));                 \
        u32x4 w00 = {pA, pC, pB, pD};                                             \
        u32x4 w01 = {pE, pG, pF, pH};                                             \
        unsigned qA = cvtpk(SC1[0], SC1[1]), qB = cvtpk(SC1[4], SC1[5]);          \
        asm("v_permlane32_swap_b32 %0, %1" : "+v"(qA), "+v"(qB));                 \
        unsigned qC = cvtpk(SC1[2], SC1[3]), qD = cvtpk(SC1[6], SC1[7]);          \
        asm("v_permlane32_swap_b32 %0, %1" : "+v"(qC), "+v"(qD));                 \
        unsigned qE = cvtpk(SC1[8], SC1[9]), qF = cvtpk(SC1[12], SC1[13]);        \
        asm("v_permlane32_swap_b32 %0, %1" : "+v"(qE), "+v"(qF));                 \
        unsigned qG = cvtpk(SC1[10], SC1[11]), qH = cvtpk(SC1[14], SC1[15]);      \
        asm("v_permlane32_swap_b32 %0, %1" : "+v"(qG), "+v"(qH));                 \
        u32x4 w10 = {qA, qC, qB, qD};                                             \
        u32x4 w11 = {qE, qG, qF, qH};                                             \
        bf16x8 pa00 = __builtin_bit_cast(bf16x8, w00);                            \
        bf16x8 pa01 = __builtin_bit_cast(bf16x8, w01);                            \
        bf16x8 pa10 = __builtin_bit_cast(bf16x8, w10);                            \
        bf16x8 pa11 = __builtin_bit_cast(bf16x8, w11);                            \
        const char* vl_ = &smem[(T) % 3][8192];                                   \
        bf16x8 va0 = ldb8(vl_ + rowA + ((hi * 16 +  0) ^ swz));                   \
        bf16x8 va1 = ldb8(vl_ + rowA + ((hi * 16 + 32) ^ swz));                   \
        bf16x8 va2 = ldb8(vl_ + rowA + ((hi * 16 + 64) ^ swz));                   \
        bf16x8 va3 = ldb8(vl_ + rowA + ((hi * 16 + 96) ^ swz));                   \
        bf16x8 vb0 = ldb8(vl_ + rowB + ((hi * 16 +  0) ^ swz));                   \
        bf16x8 vb1 = ldb8(vl_ + rowB + ((hi * 16 + 32) ^ swz));                   \
        bf16x8 vb2 = ldb8(vl_ + rowB + ((hi * 16 + 64) ^ swz));                   \
        bf16x8 vb3 = ldb8(vl_ + rowB + ((hi * 16 + 96) ^ swz));                   \
        __builtin_amdgcn_s_setprio(1);                                            \
        o0 = __builtin_amdgcn_mfma_f32_32x32x16_bf16(va0, pa00, o0, 0, 0, 0);     \
        o0 = __builtin_amdgcn_mfma_f32_32x32x16_bf16(va1, pa01, o0, 0, 0, 0);     \
        o0 = __builtin_amdgcn_mfma_f32_32x32x16_bf16(va2, pa10, o0, 0, 0, 0);     \
        o0 = __builtin_amdgcn_mfma_f32_32x32x16_bf16(va3, pa11, o0, 0, 0, 0);     \
        o1 = __builtin_amdgcn_mfma_f32_32x32x16_bf16(vb0, pa00, o1, 0, 0, 0);     \
        o1 = __builtin_amdgcn_mfma_f32_32x32x16_bf16(vb1, pa01, o1, 0, 0, 0);     \
        o1 = __builtin_amdgcn_mfma_f32_32x32x16_bf16(vb2, pa10, o1, 0, 0, 0);     \
        o1 = __builtin_amdgcn_mfma_f32_32x32x16_bf16(vb3, pa11, o1, 0, 0, 0);     \
        __builtin_amdgcn_s_setprio(0);                                            \
    }

    // prologue: stage tiles 0,1; compute S(0)
    STAGE(0, 0);
    STAGE(1, 1);
    asm volatile("s_waitcnt vmcnt(0)" ::: "memory");
    __builtin_amdgcn_s_barrier();

    f32x16 o0 = {}, o1 = {};
    f32x4 tsa = {}, tsb = {};
    f32x16 sA0 = {}, sA1 = {}, sB0, sB1;
    QK_READ(sA0, sA1, 0);

    for (int mt = 0; mt < 16; mt += 2) {
        BODY(sA0, sA1, sB0, sB1, mt);
        BODY(sB0, sB1, sA0, sA1, mt + 1);
    }
    #undef BODY
    #undef QK_READ
    #undef STAGE

    // epilogue: per-lane denominator, hi-merge, normalize, write aoT
    float l_i = (tsa[0] + tsa[1]) + (tsa[2] + tsa[3]) +
                (tsb[0] + tsb[1]) + (tsb[2] + tsb[3]);
    float l = l_i + __shfl_xor(l_i, 32);
    float inv = 1.f / l;
    unsigned short* op = aoT + ((size_t)b * NN + n) * CC + h * DH;
    #pragma unroll
    for (int q = 0; q < 4; ++q) {
        ushort4 pk;
        pk.x = bfb(o0[4 * q + 0] * inv);
        pk.y = bfb(o0[4 * q + 1] * inv);
        pk.z = bfb(o0[4 * q + 2] * inv);
        pk.w = bfb(o0[4 * q + 3] * inv);
        *reinterpret_cast<ushort4*>(op + q * 8 + hi * 4) = pk;
        ushort4 pk2;
        pk2.x = bfb(o1[4 * q + 0] * inv);
        pk2.y = bfb(o1[4 * q + 1] * inv);
        pk2.z = bfb(o1[4 * q + 2] * inv);
        pk2.w = bfb(o1[4 * q + 3] * inv);
        *reinterpret_cast<ushort4*>(op + 32 + q * 8 + hi * 4) = pk2;
    }
}

// ---------------- kernel 4: output projection, LDS-staged GEMM + bias + residual ----------------
__global__ __launch_bounds__(256, 2) void oproj2_kernel(
    const unsigned short* __restrict__ wob, const float* __restrict__ bo,
    const unsigned short* __restrict__ aoT, const float* __restrict__ x,
    float* __restrict__ out) {
    int wg = blockIdx.x;
    int xcd = wg & 7, local = wg >> 3;        // local 0..63
    int mloc = local >> 2;                     // 0..15
    int n_tile = local & 3;                    // 0..3
    int m_tile = xcd * 16 + mloc;              // 0..127
    int row0 = m_tile * 128;
    int o0t = n_tile * 128;

    __shared__ __align__(16) char As[2][16384];
    __shared__ __align__(16) char Bs[2][16384];

    int t = threadIdx.x;
    int lane = t & 63, wid = t >> 6;
    int Rl = lane >> 3;
    int csw = ((lane & 7) ^ Rl) << 4;

    const char* Ag = (const char*)aoT + (size_t)row0 * 1024;
    const char* Bg = (const char*)wob + (size_t)o0t * 1024;

    #pragma unroll
    for (int j = 0; j < 4; ++j) {
        int ii = wid * 4 + j;
        size_t ro = (size_t)(ii * 8 + Rl) * 1024 + csw;
        gload_lds16(Ag + ro, &As[0][ii * 1024]);
        gload_lds16(Bg + ro, &Bs[0][ii * 1024]);
    }
    __syncthreads();

    int wr = wid & 1, wc = wid >> 1;
    int lr = lane & 15, lg = lane >> 4;
    f32x4 acc[4][4] = {};

    for (int ks = 0; ks < 8; ++ks) {
        int cb_ = ks & 1;
        if (ks < 7) {
            int k0 = (ks + 1) * 64;
            #pragma unroll
            for (int j = 0; j < 4; ++j) {
                int ii = wid * 4 + j;
                size_t ro = (size_t)(ii * 8 + Rl) * 1024 + k0 * 2 + csw;
                gload_lds16(Ag + ro, &As[cb_ ^ 1][ii * 1024]);
                gload_lds16(Bg + ro, &Bs[cb_ ^ 1][ii * 1024]);
            }
        }
        const char* al = As[cb_];
        const char* bl = Bs[cb_];
        #pragma unroll
        for (int kk = 0; kk < 2; ++kk) {
            bf16x8 wf[4], xf[4];
            #pragma unroll
            for (int r = 0; r < 4; ++r) {
                int row = wc * 64 + r * 16 + lr;
                wf[r] = ldb8(bl + row * 128 + (((kk * 4 + lg) ^ (row & 7)) << 4));
            }
            #pragma unroll
            for (int c = 0; c < 4; ++c) {
                int row = wr * 64 + c * 16 + lr;
                xf[c] = ldb8(al + row * 128 + (((kk * 4 + lg) ^ (row & 7)) << 4));
            }
            __builtin_amdgcn_s_setprio(1);
            #pragma unroll
            for (int r = 0; r < 4; ++r)
                #pragma unroll
                for (int c = 0; c < 4; ++c)
                    acc[r][c] = __builtin_amdgcn_mfma_f32_16x16x32_bf16(wf[r], xf[c], acc[r][c], 0, 0, 0);
            __builtin_amdgcn_s_setprio(0);
        }
        __syncthreads();
    }

    #pragma unroll
    for (int r = 0; r < 4; ++r) {
        int o0 = o0t + wc * 64 + r * 16 + lg * 4;
        #pragma unroll
        for (int c = 0; c < 4; ++c) {
            int grow = row0 + wr * 64 + c * 16 + lr;
            int b = grow >> 10, n = grow & 1023;
            #pragma unroll
            for (int j = 0; j < 4; ++j) {
                size_t idx = ((size_t)b * CC + o0 + j) * NN + n;
                out[idx] = acc[r][c][j] + bo[o0 + j] + x[idx];
            }
        }
    }
}

extern "C" void kernel_launch(void* const* d_in, const int* in_sizes, int n_in,
                              void* d_out, int out_size, void* d_ws, size_t ws_size,
                              hipStream_t stream) {
    const float* x     = (const float*)d_in[0];
    const float* wq    = (const float*)d_in[1];
    const float* bq    = (const float*)d_in[2];
    const float* wk    = (const float*)d_in[3];
    const float* bk    = (const float*)d_in[4];
    const float* wv    = (const float*)d_in[5];
    const float* bv    = (const float*)d_in[6];
    const float* wo    = (const float*)d_in[7];
    const float* bo    = (const float*)d_in[8];
    const float* gamma = (const float*)d_in[9];
    const float* beta  = (const float*)d_in[10];

    char* ws = (char*)d_ws;
    const size_t WSZ = (size_t)CC * CC * 2;           // 512 KB per weight
    const size_t TEN = (size_t)BB * NN * CC * 2;      // 16.78 MB per tensor
    unsigned short* wqb = (unsigned short*)(ws);
    unsigned short* wkb = (unsigned short*)(ws + WSZ);
    unsigned short* wvb = (unsigned short*)(ws + 2 * WSZ);
    unsigned short* wob = (unsigned short*)(ws + 3 * WSZ);
    unsigned short* xnT = (unsigned short*)(ws + 4 * WSZ);
    unsigned short* qt  = (unsigned short*)(ws + 4 * WSZ + TEN);
    unsigned short* kt  = (unsigned short*)(ws + 4 * WSZ + 2 * TEN);
    unsigned short* vv  = (unsigned short*)(ws + 4 * WSZ + 3 * TEN);
    unsigned short* aoT = (unsigned short*)(ws + 4 * WSZ + 4 * TEN);

    wconv_kernel<<<dim3(256), dim3(256), 0, stream>>>(
        (const float4*)wq, (const float4*)wk, (const float4*)wv, (const float4*)wo,
        (ushort4*)wqb, (ushort4*)wkb, (ushort4*)wvb, (ushort4*)wob);
    gn_kernel<<<dim3(128), dim3(256), 0, stream>>>(x, gamma, beta, xnT);
    qkv2_kernel<<<dim3(1536), dim3(256), 0, stream>>>(
        wqb, wkb, wvb, bq, bk, bv, xnT, qt, kt, vv);
    attn7_kernel<<<dim3(1024), dim3(256), 0, stream>>>(qt, kt, vv, aoT);
    oproj2_kernel<<<dim3(512), dim3(256), 0, stream>>>(wob, bo, aoT, x, (float*)d_out);
}

// Round 8
// 130.062 us; speedup vs baseline: 1.5914x; 1.5914x over previous
//
#include <hip/hip_runtime.h>
#include <hip/hip_bf16.h>

#define BB 16
#define CC 512
#define NN 1024
#define GG 8
#define HHH 8
#define DH 64

typedef __bf16 bf16x8 __attribute__((ext_vector_type(8)));
typedef float f32x4 __attribute__((ext_vector_type(4)));
typedef float f32x16 __attribute__((ext_vector_type(16)));
typedef unsigned int u32x4 __attribute__((ext_vector_type(4)));

// scale * log2(e), folded into Q at projection time so S' = q'.k is the exp2 argument
#define QSCALE 0.18033688011116027f

__device__ __forceinline__ unsigned short bfb(float f) {
    __hip_bfloat16 h = __float2bfloat16(f);
    return __builtin_bit_cast(unsigned short, h);
}

__device__ __forceinline__ bf16x8 ldb8(const void* p) {
    return *reinterpret_cast<const bf16x8*>(p);
}

__device__ __forceinline__ unsigned int cvtpk(float lo, float hi) {
    unsigned int r;
    asm("v_cvt_pk_bf16_f32 %0, %1, %2" : "=v"(r) : "v"(lo), "v"(hi));
    return r;
}

typedef const __attribute__((address_space(1))) unsigned int* gas_ptr;
typedef __attribute__((address_space(3))) unsigned int* las_ptr;
__device__ __forceinline__ void gload_lds16(const void* g, void* l) {
    __builtin_amdgcn_global_load_lds((gas_ptr)g, (las_ptr)l, 16, 0, 0);
}

// ---------------- kernel 0: fp32 -> bf16 weight conversion ----------------
__global__ __launch_bounds__(256) void wconv_kernel(
    const float4* __restrict__ wq, const float4* __restrict__ wk,
    const float4* __restrict__ wv, const float4* __restrict__ wo,
    ushort4* __restrict__ oq, ushort4* __restrict__ ok2,
    ushort4* __restrict__ ov, ushort4* __restrict__ oo) {
    int i = blockIdx.x * 256 + threadIdx.x;  // over C*C/4 = 65536
    float4 a;
    ushort4 r;
    a = wq[i]; r.x = bfb(a.x); r.y = bfb(a.y); r.z = bfb(a.z); r.w = bfb(a.w); oq[i] = r;
    a = wk[i]; r.x = bfb(a.x); r.y = bfb(a.y); r.z = bfb(a.z); r.w = bfb(a.w); ok2[i] = r;
    a = wv[i]; r.x = bfb(a.x); r.y = bfb(a.y); r.z = bfb(a.z); r.w = bfb(a.w); ov[i] = r;
    a = wo[i]; r.x = bfb(a.x); r.y = bfb(a.y); r.z = bfb(a.z); r.w = bfb(a.w); oo[i] = r;
}

// ---------------- kernel 1: GroupNorm -> xnT [B][N][C] bf16 ----------------
__global__ __launch_bounds__(256) void gn_kernel(
    const float* __restrict__ x, const float* __restrict__ gamma,
    const float* __restrict__ beta, unsigned short* __restrict__ xnT) {
    int b = blockIdx.x >> 3, g = blockIdx.x & 7;
    const float* xg = x + ((size_t)b * CC + g * 64) * NN;
    int t = threadIdx.x;

    float s = 0.f, s2 = 0.f;
    for (int i = 0; i < 64; ++i) {
        float4 v = reinterpret_cast<const float4*>(xg)[t + i * 256];
        s += v.x + v.y + v.z + v.w;
        s2 += v.x * v.x + v.y * v.y + v.z * v.z + v.w * v.w;
    }
    #pragma unroll
    for (int m = 1; m < 64; m <<= 1) {
        s += __shfl_xor(s, m);
        s2 += __shfl_xor(s2, m);
    }
    __shared__ float red[2][4];
    int wid = t >> 6;
    if ((t & 63) == 0) { red[0][wid] = s; red[1][wid] = s2; }
    __syncthreads();
    s = red[0][0] + red[0][1] + red[0][2] + red[0][3];
    s2 = red[1][0] + red[1][1] + red[1][2] + red[1][3];
    float mean = s * (1.f / 65536.f);
    float var = s2 * (1.f / 65536.f) - mean * mean;
    float rstd = rsqrtf(var + 1e-5f);

    __shared__ unsigned short tile[64][68];
    for (int nt = 0; nt < 16; ++nt) {
        __syncthreads();
        #pragma unroll
        for (int p = 0; p < 4; ++p) {
            int cc = p * 16 + (t >> 4);
            int nn = (t & 15) * 4;
            float4 v = *reinterpret_cast<const float4*>(&xg[(size_t)cc * NN + nt * 64 + nn]);
            float ga = gamma[g * 64 + cc], be = beta[g * 64 + cc];
            float aa = rstd * ga;
            float c0 = be - mean * aa;
            ushort4 pk;
            pk.x = bfb(v.x * aa + c0);
            pk.y = bfb(v.y * aa + c0);
            pk.z = bfb(v.z * aa + c0);
            pk.w = bfb(v.w * aa + c0);
            *reinterpret_cast<ushort4*>(&tile[cc][nn]) = pk;
        }
        __syncthreads();
        #pragma unroll
        for (int p = 0; p < 16; ++p) {
            int nn = p * 4 + (t >> 6);
            int cc = t & 63;
            xnT[((size_t)b * NN + nt * 64 + nn) * CC + g * 64 + cc] = tile[cc][nn];
        }
    }
}

// ---------------- kernel 2: fused QKV projections, LDS-staged GEMM ----------------
// Q output pre-scaled by QSCALE so attention's exp2 argument is the raw QK dot.
__global__ __launch_bounds__(256, 2) void qkv2_kernel(
    const unsigned short* __restrict__ wqb, const unsigned short* __restrict__ wkb,
    const unsigned short* __restrict__ wvb,
    const float* __restrict__ bq, const float* __restrict__ bk, const float* __restrict__ bv,
    const unsigned short* __restrict__ xnT,
    unsigned short* __restrict__ qt, unsigned short* __restrict__ kt,
    unsigned short* __restrict__ vv) {
    int wg = blockIdx.x;
    int xcd = wg & 7, local = wg >> 3;       // local 0..191
    int mloc = local / 12;                    // 0..15
    int rem = local - mloc * 12;
    int n_tile = rem / 3;                     // 0..3
    int p = rem - n_tile * 3;                 // 0..2
    int m_tile = xcd * 16 + mloc;             // 0..127

    const unsigned short* w = (p == 0) ? wqb : (p == 1) ? wkb : wvb;
    const float* bias = (p == 0) ? bq : (p == 1) ? bk : bv;
    int row0 = m_tile * 128;                  // global (b,n) row
    int o0t = n_tile * 128;                   // output channel base

    __shared__ __align__(16) char As[2][16384];
    __shared__ __align__(16) char Bs[2][16384];

    int t = threadIdx.x;
    int lane = t & 63, wid = t >> 6;
    int Rl = lane >> 3;                       // 0..7 row within 8-row group
    int csw = ((lane & 7) ^ Rl) << 4;         // pre-swizzled source chunk (bytes)

    const char* Ag = (const char*)xnT + (size_t)row0 * 1024;
    const char* Bg = (const char*)w + (size_t)o0t * 1024;

    #pragma unroll
    for (int j = 0; j < 4; ++j) {             // stage k0=0 into buf 0
        int ii = wid * 4 + j;
        size_t ro = (size_t)(ii * 8 + Rl) * 1024 + csw;
        gload_lds16(Ag + ro, &As[0][ii * 1024]);
        gload_lds16(Bg + ro, &Bs[0][ii * 1024]);
    }
    __syncthreads();

    int wr = wid & 1, wc = wid >> 1;          // wave -> 64x64 quadrant
    int lr = lane & 15, lg = lane >> 4;
    f32x4 acc[4][4] = {};

    for (int ks = 0; ks < 8; ++ks) {
        int cb_ = ks & 1;
        if (ks < 7) {
            int k0 = (ks + 1) * 64;
            #pragma unroll
            for (int j = 0; j < 4; ++j) {
                int ii = wid * 4 + j;
                size_t ro = (size_t)(ii * 8 + Rl) * 1024 + k0 * 2 + csw;
                gload_lds16(Ag + ro, &As[cb_ ^ 1][ii * 1024]);
                gload_lds16(Bg + ro, &Bs[cb_ ^ 1][ii * 1024]);
            }
        }
        const char* al = As[cb_];
        const char* bl = Bs[cb_];
        #pragma unroll
        for (int kk = 0; kk < 2; ++kk) {
            bf16x8 wf[4], xf[4];
            #pragma unroll
            for (int r = 0; r < 4; ++r) {
                int row = wc * 64 + r * 16 + lr;
                wf[r] = ldb8(bl + row * 128 + (((kk * 4 + lg) ^ (row & 7)) << 4));
            }
            #pragma unroll
            for (int c = 0; c < 4; ++c) {
                int row = wr * 64 + c * 16 + lr;
                xf[c] = ldb8(al + row * 128 + (((kk * 4 + lg) ^ (row & 7)) << 4));
            }
            __builtin_amdgcn_s_setprio(1);
            #pragma unroll
            for (int r = 0; r < 4; ++r)
                #pragma unroll
                for (int c = 0; c < 4; ++c)
                    acc[r][c] = __builtin_amdgcn_mfma_f32_16x16x32_bf16(wf[r], xf[c], acc[r][c], 0, 0, 0);
            __builtin_amdgcn_s_setprio(0);
        }
        __syncthreads();
    }

    // epilogue
    #pragma unroll
    for (int r = 0; r < 4; ++r) {
        int o0 = o0t + wc * 64 + r * 16 + lg * 4;
        #pragma unroll
        for (int c = 0; c < 4; ++c) {
            int grow = row0 + wr * 64 + c * 16 + lr;
            int b = grow >> 10, n = grow & 1023;
            float v0 = acc[r][c][0] + bias[o0 + 0];
            float v1 = acc[r][c][1] + bias[o0 + 1];
            float v2 = acc[r][c][2] + bias[o0 + 2];
            float v3 = acc[r][c][3] + bias[o0 + 3];
            if (p < 2) {
                if (p == 0) { v0 *= QSCALE; v1 *= QSCALE; v2 *= QSCALE; v3 *= QSCALE; }
                unsigned short* outp = (p == 0) ? qt : kt;
                int h = o0 >> 6, d = o0 & 63;
                ushort4 pk;
                pk.x = bfb(v0); pk.y = bfb(v1); pk.z = bfb(v2); pk.w = bfb(v3);
                *reinterpret_cast<ushort4*>(outp + ((size_t)(b * HHH + h) * NN + n) * DH + d) = pk;
            } else {
                vv[((size_t)b * CC + o0 + 0) * NN + n] = bfb(v0);
                vv[((size_t)b * CC + o0 + 1) * NN + n] = bfb(v1);
                vv[((size_t)b * CC + o0 + 2) * NN + n] = bfb(v2);
                vv[((size_t)b * CC + o0 + 3) * NN + n] = bfb(v3);
            }
        }
    }
}

// ---------------- kernel 3: flash attention, S-pipelined ring-3 (attn8) ----------------
// Same structure as round-7 attn7, with the spill fixed: __launch_bounds__(256,2)
// (VGPR cap 256; round-7's (256,3) capped at ~170 < peak live set -> f32x16 scratch
// spill, 245MB of scratch writes). Per iter: QK(t+1) on matrix pipe overlaps
// exp2/pack(t) on trans/VALU pipes. vmcnt(0) at top only drains loads issued one
// full iteration earlier (cheap). Ring-3 LDS, one barrier per tile.
__global__ __launch_bounds__(256, 2) void attn8_kernel(
    const unsigned short* __restrict__ qt, const unsigned short* __restrict__ kt,
    const unsigned short* __restrict__ vv, unsigned short* __restrict__ aoT) {
    int wg = blockIdx.x;
    int bh = ((wg >> 6) << 3) + (wg & 7);  // all 8 qtiles of a head share an XCD
    int qt8 = (wg >> 3) & 7;
    int b = bh >> 3, h = bh & 7;
    int lane = threadIdx.x & 63, wid = threadIdx.x >> 6;
    int nl = lane & 31, hi = lane >> 5;
    int n = qt8 * 128 + wid * 32 + nl;

    const unsigned short* Qb = qt + (size_t)bh * NN * DH;
    const unsigned short* Kb = kt + (size_t)bh * NN * DH;
    const unsigned short* Vb = vv + ((size_t)b * CC + h * DH) * NN;

    __shared__ __align__(16) char smem[3][16384];  // ring: [K 8KB | V 8KB]

    const unsigned short* Qp = Qb + (size_t)n * DH + hi * 8;
    bf16x8 qf[4];
    qf[0] = ldb8(Qp);
    qf[1] = ldb8(Qp + 16);
    qf[2] = ldb8(Qp + 32);
    qf[3] = ldb8(Qp + 48);

    int Rl = lane >> 3;                    // 0..7
    int cs16 = 16 * ((lane & 7) ^ Rl);     // pre-swizzled col bytes (T2, rule #21)
    const char* Kc = (const char*)Kb;      // key rows, 128B stride
    const char* Vc = (const char*)Vb;      // d rows, 2048B stride

    #define STAGE(tt, buf)                                                        \
        {                                                                         \
            int m0_ = (tt) * 64;                                                  \
            _Pragma("unroll")                                                     \
            for (int j = 0; j < 2; ++j) {                                         \
                int ii = 2 * wid + j;                                             \
                int R = ii * 8 + Rl;                                              \
                gload_lds16(Kc + (size_t)(m0_ + R) * 128 + cs16,                  \
                            &smem[buf][ii * 1024]);                               \
                gload_lds16(Vc + (size_t)R * 2048 + (size_t)m0_ * 2 + cs16,       \
                            &smem[buf][8192 + ii * 1024]);                        \
            }                                                                     \
        }

    int swz = (nl & 7) << 4;
    int rowA = nl * 128, rowB = (nl + 32) * 128;

    // QK for tile TT from ring slot TT%3 into SN0/SN1 (zero-init by caller)
    #define QK_READ(SN0, SN1, TT)                                                 \
        {                                                                         \
            const char* kl_ = &smem[(TT) % 3][0];                                 \
            bf16x8 k0_ = ldb8(kl_ + rowA + ((hi * 16 +  0) ^ swz));               \
            bf16x8 k1_ = ldb8(kl_ + rowA + ((hi * 16 + 32) ^ swz));               \
            bf16x8 k2_ = ldb8(kl_ + rowA + ((hi * 16 + 64) ^ swz));               \
            bf16x8 k3_ = ldb8(kl_ + rowA + ((hi * 16 + 96) ^ swz));               \
            bf16x8 l0_ = ldb8(kl_ + rowB + ((hi * 16 +  0) ^ swz));               \
            bf16x8 l1_ = ldb8(kl_ + rowB + ((hi * 16 + 32) ^ swz));               \
            bf16x8 l2_ = ldb8(kl_ + rowB + ((hi * 16 + 64) ^ swz));               \
            bf16x8 l3_ = ldb8(kl_ + rowB + ((hi * 16 + 96) ^ swz));               \
            __builtin_amdgcn_s_setprio(1);                                        \
            SN0 = __builtin_amdgcn_mfma_f32_32x32x16_bf16(k0_, qf[0], SN0, 0, 0, 0); \
            SN1 = __builtin_amdgcn_mfma_f32_32x32x16_bf16(l0_, qf[0], SN1, 0, 0, 0); \
            SN0 = __builtin_amdgcn_mfma_f32_32x32x16_bf16(k1_, qf[1], SN0, 0, 0, 0); \
            SN1 = __builtin_amdgcn_mfma_f32_32x32x16_bf16(l1_, qf[1], SN1, 0, 0, 0); \
            SN0 = __builtin_amdgcn_mfma_f32_32x32x16_bf16(k2_, qf[2], SN0, 0, 0, 0); \
            SN1 = __builtin_amdgcn_mfma_f32_32x32x16_bf16(l2_, qf[2], SN1, 0, 0, 0); \
            SN0 = __builtin_amdgcn_mfma_f32_32x32x16_bf16(k3_, qf[3], SN0, 0, 0, 0); \
            SN1 = __builtin_amdgcn_mfma_f32_32x32x16_bf16(l3_, qf[3], SN1, 0, 0, 0); \
            __builtin_amdgcn_s_setprio(0);                                        \
        }

    // full per-tile body: consume SC (tile T), produce SN (tile T+1)
    #define BODY(SC0, SC1, SN0, SN1, T)                                           \
    {                                                                             \
        asm volatile("s_waitcnt vmcnt(0)" ::: "memory");                          \
        __builtin_amdgcn_s_barrier();                                             \
        if ((T) < 14) STAGE((T) + 2, ((T) + 2) % 3);                              \
        if ((T) < 15) {                                                           \
            SN0 = (f32x16){};                                                     \
            SN1 = (f32x16){};                                                     \
            QK_READ(SN0, SN1, (T) + 1);                                           \
        }                                                                         \
        _Pragma("unroll")                                                         \
        for (int e = 0; e < 16; ++e) SC0[e] = __builtin_amdgcn_exp2f(SC0[e]);     \
        _Pragma("unroll")                                                         \
        for (int e = 0; e < 16; ++e) SC1[e] = __builtin_amdgcn_exp2f(SC1[e]);     \
        _Pragma("unroll")                                                         \
        for (int e = 0; e < 4; ++e) {                                             \
            tsa[e] += (SC0[e] + SC0[e + 4]) + (SC0[e + 8] + SC0[e + 12]);         \
            tsa[e] += (SC1[e] + SC1[e + 4]) + (SC1[e + 8] + SC1[e + 12]);         \
        }                                                                         \
        unsigned pA = cvtpk(SC0[0], SC0[1]), pB = cvtpk(SC0[4], SC0[5]);          \
        asm("v_permlane32_swap_b32 %0, %1" : "+v"(pA), "+v"(pB));                 \
        unsigned pC = cvtpk(SC0[2], SC0[3]), pD = cvtpk(SC0[6], SC0[7]);          \
        asm("v_permlane32_swap_b32 %0, %1" : "+v"(pC), "+v"(pD));                 \
        unsigned pE = cvtpk(SC0[8], SC0[9]), pF = cvtpk(SC0[12], SC0[13]);        \
        asm("v_permlane32_swap_b32 %0, %1" : "+v"(pE), "+v"(pF));                 \
        unsigned pG = cvtpk(SC0[10], SC0[11]), pH = cvtpk(SC0[14], SC0[15]);      \
        asm("v_permlane32_swap_b32 %0, %1" : "+v"(pG), "+v"(pH));                 \
        u32x4 w00 = {pA, pC, pB, pD};                                             \
        u32x4 w01 = {pE, pG, pF, pH};                                             \
        unsigned qA = cvtpk(SC1[0], SC1[1]), qB = cvtpk(SC1[4], SC1[5]);          \
        asm("v_permlane32_swap_b32 %0, %1" : "+v"(qA), "+v"(qB));                 \
        unsigned qC = cvtpk(SC1[2], SC1[3]), qD = cvtpk(SC1[6], SC1[7]);          \
        asm("v_permlane32_swap_b32 %0, %1" : "+v"(qC), "+v"(qD));                 \
        unsigned qE = cvtpk(SC1[8], SC1[9]), qF = cvtpk(SC1[12], SC1[13]);        \
        asm("v_permlane32_swap_b32 %0, %1" : "+v"(qE), "+v"(qF));                 \
        unsigned qG = cvtpk(SC1[10], SC1[11]), qH = cvtpk(SC1[14], SC1[15]);      \
        asm("v_permlane32_swap_b32 %0, %1" : "+v"(qG), "+v"(qH));                 \
        u32x4 w10 = {qA, qC, qB, qD};                                             \
        u32x4 w11 = {qE, qG, qF, qH};                                             \
        bf16x8 pa00 = __builtin_bit_cast(bf16x8, w00);                            \
        bf16x8 pa01 = __builtin_bit_cast(bf16x8, w01);                            \
        bf16x8 pa10 = __builtin_bit_cast(bf16x8, w10);                            \
        bf16x8 pa11 = __builtin_bit_cast(bf16x8, w11);                            \
        const char* vl_ = &smem[(T) % 3][8192];                                   \
        bf16x8 va0 = ldb8(vl_ + rowA + ((hi * 16 +  0) ^ swz));                   \
        bf16x8 va1 = ldb8(vl_ + rowA + ((hi * 16 + 32) ^ swz));                   \
        bf16x8 va2 = ldb8(vl_ + rowA + ((hi * 16 + 64) ^ swz));                   \
        bf16x8 va3 = ldb8(vl_ + rowA + ((hi * 16 + 96) ^ swz));                   \
        bf16x8 vb0 = ldb8(vl_ + rowB + ((hi * 16 +  0) ^ swz));                   \
        bf16x8 vb1 = ldb8(vl_ + rowB + ((hi * 16 + 32) ^ swz));                   \
        bf16x8 vb2 = ldb8(vl_ + rowB + ((hi * 16 + 64) ^ swz));                   \
        bf16x8 vb3 = ldb8(vl_ + rowB + ((hi * 16 + 96) ^ swz));                   \
        __builtin_amdgcn_s_setprio(1);                                            \
        o0 = __builtin_amdgcn_mfma_f32_32x32x16_bf16(va0, pa00, o0, 0, 0, 0);     \
        o0 = __builtin_amdgcn_mfma_f32_32x32x16_bf16(va1, pa01, o0, 0, 0, 0);     \
        o0 = __builtin_amdgcn_mfma_f32_32x32x16_bf16(va2, pa10, o0, 0, 0, 0);     \
        o0 = __builtin_amdgcn_mfma_f32_32x32x16_bf16(va3, pa11, o0, 0, 0, 0);     \
        o1 = __builtin_amdgcn_mfma_f32_32x32x16_bf16(vb0, pa00, o1, 0, 0, 0);     \
        o1 = __builtin_amdgcn_mfma_f32_32x32x16_bf16(vb1, pa01, o1, 0, 0, 0);     \
        o1 = __builtin_amdgcn_mfma_f32_32x32x16_bf16(vb2, pa10, o1, 0, 0, 0);     \
        o1 = __builtin_amdgcn_mfma_f32_32x32x16_bf16(vb3, pa11, o1, 0, 0, 0);     \
        __builtin_amdgcn_s_setprio(0);                                            \
    }

    // prologue: stage tiles 0,1; compute S(0)
    STAGE(0, 0);
    STAGE(1, 1);
    asm volatile("s_waitcnt vmcnt(0)" ::: "memory");
    __builtin_amdgcn_s_barrier();

    f32x16 o0 = {}, o1 = {};
    f32x4 tsa = {};
    f32x16 sA0 = {}, sA1 = {}, sB0, sB1;
    QK_READ(sA0, sA1, 0);

    for (int mt = 0; mt < 16; mt += 2) {
        BODY(sA0, sA1, sB0, sB1, mt);
        BODY(sB0, sB1, sA0, sA1, mt + 1);
    }
    #undef BODY
    #undef QK_READ
    #undef STAGE

    // epilogue: per-lane denominator, hi-merge, normalize, write aoT
    float l_i = (tsa[0] + tsa[1]) + (tsa[2] + tsa[3]);
    float l = l_i + __shfl_xor(l_i, 32);
    float inv = 1.f / l;
    unsigned short* op = aoT + ((size_t)b * NN + n) * CC + h * DH;
    #pragma unroll
    for (int q = 0; q < 4; ++q) {
        ushort4 pk;
        pk.x = bfb(o0[4 * q + 0] * inv);
        pk.y = bfb(o0[4 * q + 1] * inv);
        pk.z = bfb(o0[4 * q + 2] * inv);
        pk.w = bfb(o0[4 * q + 3] * inv);
        *reinterpret_cast<ushort4*>(op + q * 8 + hi * 4) = pk;
        ushort4 pk2;
        pk2.x = bfb(o1[4 * q + 0] * inv);
        pk2.y = bfb(o1[4 * q + 1] * inv);
        pk2.z = bfb(o1[4 * q + 2] * inv);
        pk2.w = bfb(o1[4 * q + 3] * inv);
        *reinterpret_cast<ushort4*>(op + 32 + q * 8 + hi * 4) = pk2;
    }
}

// ---------------- kernel 4: output projection, LDS-staged GEMM + bias + residual ----------------
__global__ __launch_bounds__(256, 2) void oproj2_kernel(
    const unsigned short* __restrict__ wob, const float* __restrict__ bo,
    const unsigned short* __restrict__ aoT, const float* __restrict__ x,
    float* __restrict__ out) {
    int wg = blockIdx.x;
    int xcd = wg & 7, local = wg >> 3;        // local 0..63
    int mloc = local >> 2;                     // 0..15
    int n_tile = local & 3;                    // 0..3
    int m_tile = xcd * 16 + mloc;              // 0..127
    int row0 = m_tile * 128;
    int o0t = n_tile * 128;

    __shared__ __align__(16) char As[2][16384];
    __shared__ __align__(16) char Bs[2][16384];

    int t = threadIdx.x;
    int lane = t & 63, wid = t >> 6;
    int Rl = lane >> 3;
    int csw = ((lane & 7) ^ Rl) << 4;

    const char* Ag = (const char*)aoT + (size_t)row0 * 1024;
    const char* Bg = (const char*)wob + (size_t)o0t * 1024;

    #pragma unroll
    for (int j = 0; j < 4; ++j) {
        int ii = wid * 4 + j;
        size_t ro = (size_t)(ii * 8 + Rl) * 1024 + csw;
        gload_lds16(Ag + ro, &As[0][ii * 1024]);
        gload_lds16(Bg + ro, &Bs[0][ii * 1024]);
    }
    __syncthreads();

    int wr = wid & 1, wc = wid >> 1;
    int lr = lane & 15, lg = lane >> 4;
    f32x4 acc[4][4] = {};

    for (int ks = 0; ks < 8; ++ks) {
        int cb_ = ks & 1;
        if (ks < 7) {
            int k0 = (ks + 1) * 64;
            #pragma unroll
            for (int j = 0; j < 4; ++j) {
                int ii = wid * 4 + j;
                size_t ro = (size_t)(ii * 8 + Rl) * 1024 + k0 * 2 + csw;
                gload_lds16(Ag + ro, &As[cb_ ^ 1][ii * 1024]);
                gload_lds16(Bg + ro, &Bs[cb_ ^ 1][ii * 1024]);
            }
        }
        const char* al = As[cb_];
        const char* bl = Bs[cb_];
        #pragma unroll
        for (int kk = 0; kk < 2; ++kk) {
            bf16x8 wf[4], xf[4];
            #pragma unroll
            for (int r = 0; r < 4; ++r) {
                int row = wc * 64 + r * 16 + lr;
                wf[r] = ldb8(bl + row * 128 + (((kk * 4 + lg) ^ (row & 7)) << 4));
            }
            #pragma unroll
            for (int c = 0; c < 4; ++c) {
                int row = wr * 64 + c * 16 + lr;
                xf[c] = ldb8(al + row * 128 + (((kk * 4 + lg) ^ (row & 7)) << 4));
            }
            __builtin_amdgcn_s_setprio(1);
            #pragma unroll
            for (int r = 0; r < 4; ++r)
                #pragma unroll
                for (int c = 0; c < 4; ++c)
                    acc[r][c] = __builtin_amdgcn_mfma_f32_16x16x32_bf16(wf[r], xf[c], acc[r][c], 0, 0, 0);
            __builtin_amdgcn_s_setprio(0);
        }
        __syncthreads();
    }

    #pragma unroll
    for (int r = 0; r < 4; ++r) {
        int o0 = o0t + wc * 64 + r * 16 + lg * 4;
        #pragma unroll
        for (int c = 0; c < 4; ++c) {
            int grow = row0 + wr * 64 + c * 16 + lr;
            int b = grow >> 10, n = grow & 1023;
            #pragma unroll
            for (int j = 0; j < 4; ++j) {
                size_t idx = ((size_t)b * CC + o0 + j) * NN + n;
                out[idx] = acc[r][c][j] + bo[o0 + j] + x[idx];
            }
        }
    }
}

extern "C" void kernel_launch(void* const* d_in, const int* in_sizes, int n_in,
                              void* d_out, int out_size, void* d_ws, size_t ws_size,
                              hipStream_t stream) {
    const float* x     = (const float*)d_in[0];
    const float* wq    = (const float*)d_in[1];
    const float* bq    = (const float*)d_in[2];
    const float* wk    = (const float*)d_in[3];
    const float* bk    = (const float*)d_in[4];
    const float* wv    = (const float*)d_in[5];
    const float* bv    = (const float*)d_in[6];
    const float* wo    = (const float*)d_in[7];
    const float* bo    = (const float*)d_in[8];
    const float* gamma = (const float*)d_in[9];
    const float* beta  = (const float*)d_in[10];

    char* ws = (char*)d_ws;
    const size_t WSZ = (size_t)CC * CC * 2;           // 512 KB per weight
    const size_t TEN = (size_t)BB * NN * CC * 2;      // 16.78 MB per tensor
    unsigned short* wqb = (unsigned short*)(ws);
    unsigned short* wkb = (unsigned short*)(ws + WSZ);
    unsigned short* wvb = (unsigned short*)(ws + 2 * WSZ);
    unsigned short* wob = (unsigned short*)(ws + 3 * WSZ);
    unsigned short* xnT = (unsigned short*)(ws + 4 * WSZ);
    unsigned short* qt  = (unsigned short*)(ws + 4 * WSZ + TEN);
    unsigned short* kt  = (unsigned short*)(ws + 4 * WSZ + 2 * TEN);
    unsigned short* vv  = (unsigned short*)(ws + 4 * WSZ + 3 * TEN);
    unsigned short* aoT = (unsigned short*)(ws + 4 * WSZ + 4 * TEN);

    wconv_kernel<<<dim3(256), dim3(256), 0, stream>>>(
        (const float4*)wq, (const float4*)wk, (const float4*)wv, (const float4*)wo,
        (ushort4*)wqb, (ushort4*)wkb, (ushort4*)wvb, (ushort4*)wob);
    gn_kernel<<<dim3(128), dim3(256), 0, stream>>>(x, gamma, beta, xnT);
    qkv2_kernel<<<dim3(1536), dim3(256), 0, stream>>>(
        wqb, wkb, wvb, bq, bk, bv, xnT, qt, kt, vv);
    attn8_kernel<<<dim3(1024), dim3(256), 0, stream>>>(qt, kt, vv, aoT);
    oproj2_kernel<<<dim3(512), dim3(256), 0, stream>>>(wob, bo, aoT, x, (float*)d_out);
}

// Round 9
// 124.926 us; speedup vs baseline: 1.6568x; 1.0411x over previous
//
#include <hip/hip_runtime.h>
#include <hip/hip_bf16.h>

#define BB 16
#define CC 512
#define NN 1024
#define GG 8
#define HHH 8
#define DH 64

typedef __bf16 bf16x8 __attribute__((ext_vector_type(8)));
typedef float f32x4 __attribute__((ext_vector_type(4)));
typedef float f32x16 __attribute__((ext_vector_type(16)));
typedef unsigned int u32x4 __attribute__((ext_vector_type(4)));

// scale * log2(e), folded into Q at projection time so S' = q'.k is the exp2 argument
#define QSCALE 0.18033688011116027f

__device__ __forceinline__ unsigned short bfb(float f) {
    __hip_bfloat16 h = __float2bfloat16(f);
    return __builtin_bit_cast(unsigned short, h);
}

__device__ __forceinline__ bf16x8 ldb8(const void* p) {
    return *reinterpret_cast<const bf16x8*>(p);
}

__device__ __forceinline__ unsigned int cvtpk(float lo, float hi) {
    unsigned int r;
    asm("v_cvt_pk_bf16_f32 %0, %1, %2" : "=v"(r) : "v"(lo), "v"(hi));
    return r;
}

typedef const __attribute__((address_space(1))) unsigned int* gas_ptr;
typedef __attribute__((address_space(3))) unsigned int* las_ptr;
__device__ __forceinline__ void gload_lds16(const void* g, void* l) {
    __builtin_amdgcn_global_load_lds((gas_ptr)g, (las_ptr)l, 16, 0, 0);
}

// ---------------- kernel 0: fp32 -> bf16 weight conversion ----------------
__global__ __launch_bounds__(256) void wconv_kernel(
    const float4* __restrict__ wq, const float4* __restrict__ wk,
    const float4* __restrict__ wv, const float4* __restrict__ wo,
    ushort4* __restrict__ oq, ushort4* __restrict__ ok2,
    ushort4* __restrict__ ov, ushort4* __restrict__ oo) {
    int i = blockIdx.x * 256 + threadIdx.x;  // over C*C/4 = 65536
    float4 a;
    ushort4 r;
    a = wq[i]; r.x = bfb(a.x); r.y = bfb(a.y); r.z = bfb(a.z); r.w = bfb(a.w); oq[i] = r;
    a = wk[i]; r.x = bfb(a.x); r.y = bfb(a.y); r.z = bfb(a.z); r.w = bfb(a.w); ok2[i] = r;
    a = wv[i]; r.x = bfb(a.x); r.y = bfb(a.y); r.z = bfb(a.z); r.w = bfb(a.w); ov[i] = r;
    a = wo[i]; r.x = bfb(a.x); r.y = bfb(a.y); r.z = bfb(a.z); r.w = bfb(a.w); oo[i] = r;
}

// ---------------- kernel 1: GroupNorm -> xnT [B][N][C] bf16 (1024 threads) ----------------
// grid 128 = (b,g); round-8 version ran 256 threads -> thread-starved at 0.5 blocks/CU.
// Now 16 waves: stats over all, then 4 independent 256-thread transpose groups on
// interleaved 64-n stripes, each with a private LDS tile.
__global__ __launch_bounds__(1024) void gn_kernel(
    const float* __restrict__ x, const float* __restrict__ gamma,
    const float* __restrict__ beta, unsigned short* __restrict__ xnT) {
    int b = blockIdx.x >> 3, g = blockIdx.x & 7;
    const float* xg = x + ((size_t)b * CC + g * 64) * NN;
    int t = threadIdx.x;

    float s = 0.f, s2 = 0.f;
    #pragma unroll
    for (int i = 0; i < 16; ++i) {
        float4 v = reinterpret_cast<const float4*>(xg)[t + i * 1024];
        s += v.x + v.y + v.z + v.w;
        s2 += v.x * v.x + v.y * v.y + v.z * v.z + v.w * v.w;
    }
    #pragma unroll
    for (int m = 1; m < 64; m <<= 1) {
        s += __shfl_xor(s, m);
        s2 += __shfl_xor(s2, m);
    }
    __shared__ float red[2][16];
    int wid = t >> 6;
    if ((t & 63) == 0) { red[0][wid] = s; red[1][wid] = s2; }
    __syncthreads();
    s = 0.f; s2 = 0.f;
    #pragma unroll
    for (int i = 0; i < 16; ++i) { s += red[0][i]; s2 += red[1][i]; }
    float mean = s * (1.f / 65536.f);
    float var = s2 * (1.f / 65536.f) - mean * mean;
    float rstd = rsqrtf(var + 1e-5f);

    __shared__ unsigned short tile[4][64][68];  // one tile per 256-thread group
    int grp = t >> 8;        // 0..3
    int tl = t & 255;
    for (int nt = grp; nt < 16; nt += 4) {
        __syncthreads();
        // read 64c x 64n stripe (coalesced), normalize, store to LDS
        #pragma unroll
        for (int p = 0; p < 4; ++p) {
            int cc = p * 16 + (tl >> 4);
            int nn = (tl & 15) * 4;
            float4 v = *reinterpret_cast<const float4*>(&xg[(size_t)cc * NN + nt * 64 + nn]);
            float ga = gamma[g * 64 + cc], be = beta[g * 64 + cc];
            float aa = rstd * ga;
            float c0 = be - mean * aa;
            ushort4 pk;
            pk.x = bfb(v.x * aa + c0);
            pk.y = bfb(v.y * aa + c0);
            pk.z = bfb(v.z * aa + c0);
            pk.w = bfb(v.w * aa + c0);
            *reinterpret_cast<ushort4*>(&tile[grp][cc][nn]) = pk;
        }
        __syncthreads();
        // write transposed: consecutive threads -> consecutive c (coalesced)
        #pragma unroll
        for (int p = 0; p < 16; ++p) {
            int nn = p * 4 + (tl >> 6);
            int cc = tl & 63;
            xnT[((size_t)b * NN + nt * 64 + nn) * CC + g * 64 + cc] = tile[grp][cc][nn];
        }
    }
}

// ---------------- kernel 2: fused QKV projections, LDS-staged GEMM ----------------
// Q output pre-scaled by QSCALE so attention's exp2 argument is the raw QK dot.
__global__ __launch_bounds__(256, 2) void qkv2_kernel(
    const unsigned short* __restrict__ wqb, const unsigned short* __restrict__ wkb,
    const unsigned short* __restrict__ wvb,
    const float* __restrict__ bq, const float* __restrict__ bk, const float* __restrict__ bv,
    const unsigned short* __restrict__ xnT,
    unsigned short* __restrict__ qt, unsigned short* __restrict__ kt,
    unsigned short* __restrict__ vv) {
    int wg = blockIdx.x;
    int xcd = wg & 7, local = wg >> 3;       // local 0..191
    int mloc = local / 12;                    // 0..15
    int rem = local - mloc * 12;
    int n_tile = rem / 3;                     // 0..3
    int p = rem - n_tile * 3;                 // 0..2
    int m_tile = xcd * 16 + mloc;             // 0..127

    const unsigned short* w = (p == 0) ? wqb : (p == 1) ? wkb : wvb;
    const float* bias = (p == 0) ? bq : (p == 1) ? bk : bv;
    int row0 = m_tile * 128;                  // global (b,n) row
    int o0t = n_tile * 128;                   // output channel base

    __shared__ __align__(16) char As[2][16384];
    __shared__ __align__(16) char Bs[2][16384];

    int t = threadIdx.x;
    int lane = t & 63, wid = t >> 6;
    int Rl = lane >> 3;                       // 0..7 row within 8-row group
    int csw = ((lane & 7) ^ Rl) << 4;         // pre-swizzled source chunk (bytes)

    const char* Ag = (const char*)xnT + (size_t)row0 * 1024;
    const char* Bg = (const char*)w + (size_t)o0t * 1024;

    #pragma unroll
    for (int j = 0; j < 4; ++j) {             // stage k0=0 into buf 0
        int ii = wid * 4 + j;
        size_t ro = (size_t)(ii * 8 + Rl) * 1024 + csw;
        gload_lds16(Ag + ro, &As[0][ii * 1024]);
        gload_lds16(Bg + ro, &Bs[0][ii * 1024]);
    }
    __syncthreads();

    int wr = wid & 1, wc = wid >> 1;          // wave -> 64x64 quadrant
    int lr = lane & 15, lg = lane >> 4;
    f32x4 acc[4][4] = {};

    for (int ks = 0; ks < 8; ++ks) {
        int cb_ = ks & 1;
        if (ks < 7) {
            int k0 = (ks + 1) * 64;
            #pragma unroll
            for (int j = 0; j < 4; ++j) {
                int ii = wid * 4 + j;
                size_t ro = (size_t)(ii * 8 + Rl) * 1024 + k0 * 2 + csw;
                gload_lds16(Ag + ro, &As[cb_ ^ 1][ii * 1024]);
                gload_lds16(Bg + ro, &Bs[cb_ ^ 1][ii * 1024]);
            }
        }
        const char* al = As[cb_];
        const char* bl = Bs[cb_];
        #pragma unroll
        for (int kk = 0; kk < 2; ++kk) {
            bf16x8 wf[4], xf[4];
            #pragma unroll
            for (int r = 0; r < 4; ++r) {
                int row = wc * 64 + r * 16 + lr;
                wf[r] = ldb8(bl + row * 128 + (((kk * 4 + lg) ^ (row & 7)) << 4));
            }
            #pragma unroll
            for (int c = 0; c < 4; ++c) {
                int row = wr * 64 + c * 16 + lr;
                xf[c] = ldb8(al + row * 128 + (((kk * 4 + lg) ^ (row & 7)) << 4));
            }
            __builtin_amdgcn_s_setprio(1);
            #pragma unroll
            for (int r = 0; r < 4; ++r)
                #pragma unroll
                for (int c = 0; c < 4; ++c)
                    acc[r][c] = __builtin_amdgcn_mfma_f32_16x16x32_bf16(wf[r], xf[c], acc[r][c], 0, 0, 0);
            __builtin_amdgcn_s_setprio(0);
        }
        __syncthreads();
    }

    // epilogue
    #pragma unroll
    for (int r = 0; r < 4; ++r) {
        int o0 = o0t + wc * 64 + r * 16 + lg * 4;
        #pragma unroll
        for (int c = 0; c < 4; ++c) {
            int grow = row0 + wr * 64 + c * 16 + lr;
            int b = grow >> 10, n = grow & 1023;
            float v0 = acc[r][c][0] + bias[o0 + 0];
            float v1 = acc[r][c][1] + bias[o0 + 1];
            float v2 = acc[r][c][2] + bias[o0 + 2];
            float v3 = acc[r][c][3] + bias[o0 + 3];
            if (p < 2) {
                if (p == 0) { v0 *= QSCALE; v1 *= QSCALE; v2 *= QSCALE; v3 *= QSCALE; }
                unsigned short* outp = (p == 0) ? qt : kt;
                int h = o0 >> 6, d = o0 & 63;
                ushort4 pk;
                pk.x = bfb(v0); pk.y = bfb(v1); pk.z = bfb(v2); pk.w = bfb(v3);
                *reinterpret_cast<ushort4*>(outp + ((size_t)(b * HHH + h) * NN + n) * DH + d) = pk;
            } else {
                vv[((size_t)b * CC + o0 + 0) * NN + n] = bfb(v0);
                vv[((size_t)b * CC + o0 + 1) * NN + n] = bfb(v1);
                vv[((size_t)b * CC + o0 + 2) * NN + n] = bfb(v2);
                vv[((size_t)b * CC + o0 + 3) * NN + n] = bfb(v3);
            }
        }
    }
}

// ---------------- kernel 3: flash attention, max-free softmax (attn4, best: 47.5us) ----------------
__global__ __launch_bounds__(256, 2) void attn4_kernel(
    const unsigned short* __restrict__ qt, const unsigned short* __restrict__ kt,
    const unsigned short* __restrict__ vv, unsigned short* __restrict__ aoT) {
    int wg = blockIdx.x;
    int bh = ((wg >> 6) << 3) + (wg & 7);  // all 8 qtiles of a head share an XCD
    int qt8 = (wg >> 3) & 7;
    int b = bh >> 3, h = bh & 7;
    int lane = threadIdx.x & 63, wid = threadIdx.x >> 6;
    int nl = lane & 31, hi = lane >> 5;
    int n = qt8 * 128 + wid * 32 + nl;

    const unsigned short* Qb = qt + (size_t)bh * NN * DH;
    const unsigned short* Kb = kt + (size_t)bh * NN * DH;
    const unsigned short* Vb = vv + ((size_t)b * CC + h * DH) * NN;

    __shared__ __align__(16) char smem[2][16384];  // [buf][ K 8KB | V 8KB ]

    const unsigned short* Qp = Qb + (size_t)n * DH + hi * 8;
    bf16x8 qf[4];
    qf[0] = ldb8(Qp);
    qf[1] = ldb8(Qp + 16);
    qf[2] = ldb8(Qp + 32);
    qf[3] = ldb8(Qp + 48);

    int Rl = lane >> 3;                    // 0..7
    int cs16 = 16 * ((lane & 7) ^ Rl);     // pre-swizzled col bytes
    const char* Kc = (const char*)Kb;      // row stride 128B
    const char* Vc = (const char*)Vb;      // row stride 2048B

    #pragma unroll
    for (int j = 0; j < 2; ++j) {
        int ii = 2 * wid + j;
        int R = ii * 8 + Rl;
        gload_lds16(Kc + (size_t)R * 128 + cs16, &smem[0][ii * 1024]);
        gload_lds16(Vc + (size_t)R * 2048 + cs16, &smem[0][8192 + ii * 1024]);
    }
    __syncthreads();

    f32x16 o0 = {}, o1 = {};
    float l_i = 0.f;
    int cur = 0;

    for (int mt = 0; mt < 16; ++mt) {
        if (mt < 15) {
            int m0n = (mt + 1) * 64;
            #pragma unroll
            for (int j = 0; j < 2; ++j) {
                int ii = 2 * wid + j;
                int R = ii * 8 + Rl;
                gload_lds16(Kc + (size_t)(m0n + R) * 128 + cs16, &smem[cur ^ 1][ii * 1024]);
                gload_lds16(Vc + (size_t)R * 2048 + (size_t)m0n * 2 + cs16,
                            &smem[cur ^ 1][8192 + ii * 1024]);
            }
        }

        const char* kl = &smem[cur][0];
        const char* vl = &smem[cur][8192];
        int swz = (nl & 7) << 4;
        int rowA = nl * 128, rowB = (nl + 32) * 128;

        bf16x8 ka[4], kbf[4];
        #pragma unroll
        for (int ks = 0; ks < 4; ++ks) {
            int cb = (hi * 16 + ks * 32) ^ swz;
            ka[ks]  = ldb8(kl + rowA + cb);
            kbf[ks] = ldb8(kl + rowB + cb);
        }

        f32x16 s0 = {}, s1 = {};
        __builtin_amdgcn_s_setprio(1);
        #pragma unroll
        for (int ks = 0; ks < 4; ++ks) {
            s0 = __builtin_amdgcn_mfma_f32_32x32x16_bf16(ka[ks], qf[ks], s0, 0, 0, 0);
            s1 = __builtin_amdgcn_mfma_f32_32x32x16_bf16(kbf[ks], qf[ks], s1, 0, 0, 0);
        }
        __builtin_amdgcn_s_setprio(0);

        bf16x8 va[4], vbf[4];
        #pragma unroll
        for (int ks = 0; ks < 4; ++ks) {
            int cb = (hi * 16 + ks * 32) ^ swz;
            va[ks]  = ldb8(vl + rowA + cb);
            vbf[ks] = ldb8(vl + rowB + cb);
        }

        // ---- max-free softmax: P = 2^S', accumulate l ----
        #pragma unroll
        for (int e = 0; e < 16; ++e) s0[e] = __builtin_amdgcn_exp2f(s0[e]);
        #pragma unroll
        for (int e = 0; e < 16; ++e) s1[e] = __builtin_amdgcn_exp2f(s1[e]);
        float ts[16];
        #pragma unroll
        for (int e = 0; e < 16; ++e) ts[e] = s0[e] + s1[e];
        #pragma unroll
        for (int st = 8; st; st >>= 1)
            #pragma unroll
            for (int e = 0; e < st; ++e) ts[e] += ts[e + st];
        l_i += ts[0];

        // ---- pack P -> bf16 B-fragments (cvt_pk + permlane32_swap) ----
        unsigned pA = cvtpk(s0[0], s0[1]), pB = cvtpk(s0[4], s0[5]);
        asm("v_permlane32_swap_b32 %0, %1" : "+v"(pA), "+v"(pB));
        unsigned pC = cvtpk(s0[2], s0[3]), pD = cvtpk(s0[6], s0[7]);
        asm("v_permlane32_swap_b32 %0, %1" : "+v"(pC), "+v"(pD));
        unsigned pE = cvtpk(s0[8], s0[9]), pF = cvtpk(s0[12], s0[13]);
        asm("v_permlane32_swap_b32 %0, %1" : "+v"(pE), "+v"(pF));
        unsigned pG = cvtpk(s0[10], s0[11]), pH = cvtpk(s0[14], s0[15]);
        asm("v_permlane32_swap_b32 %0, %1" : "+v"(pG), "+v"(pH));
        u32x4 w00 = {pA, pC, pB, pD};
        u32x4 w01 = {pE, pG, pF, pH};
        unsigned qA = cvtpk(s1[0], s1[1]), qB = cvtpk(s1[4], s1[5]);
        asm("v_permlane32_swap_b32 %0, %1" : "+v"(qA), "+v"(qB));
        unsigned qC = cvtpk(s1[2], s1[3]), qD = cvtpk(s1[6], s1[7]);
        asm("v_permlane32_swap_b32 %0, %1" : "+v"(qC), "+v"(qD));
        unsigned qE = cvtpk(s1[8], s1[9]), qF = cvtpk(s1[12], s1[13]);
        asm("v_permlane32_swap_b32 %0, %1" : "+v"(qE), "+v"(qF));
        unsigned qG = cvtpk(s1[10], s1[11]), qH = cvtpk(s1[14], s1[15]);
        asm("v_permlane32_swap_b32 %0, %1" : "+v"(qG), "+v"(qH));
        u32x4 w10 = {qA, qC, qB, qD};
        u32x4 w11 = {qE, qG, qF, qH};

        bf16x8 pa00 = __builtin_bit_cast(bf16x8, w00);
        bf16x8 pa01 = __builtin_bit_cast(bf16x8, w01);
        bf16x8 pa10 = __builtin_bit_cast(bf16x8, w10);
        bf16x8 pa11 = __builtin_bit_cast(bf16x8, w11);

        // ---- PV: O^T[d][n] += V^T[d][m] P^T[m][n] ----
        __builtin_amdgcn_s_setprio(1);
        o0 = __builtin_amdgcn_mfma_f32_32x32x16_bf16(va[0], pa00, o0, 0, 0, 0);
        o0 = __builtin_amdgcn_mfma_f32_32x32x16_bf16(va[1], pa01, o0, 0, 0, 0);
        o0 = __builtin_amdgcn_mfma_f32_32x32x16_bf16(va[2], pa10, o0, 0, 0, 0);
        o0 = __builtin_amdgcn_mfma_f32_32x32x16_bf16(va[3], pa11, o0, 0, 0, 0);
        o1 = __builtin_amdgcn_mfma_f32_32x32x16_bf16(vbf[0], pa00, o1, 0, 0, 0);
        o1 = __builtin_amdgcn_mfma_f32_32x32x16_bf16(vbf[1], pa01, o1, 0, 0, 0);
        o1 = __builtin_amdgcn_mfma_f32_32x32x16_bf16(vbf[2], pa10, o1, 0, 0, 0);
        o1 = __builtin_amdgcn_mfma_f32_32x32x16_bf16(vbf[3], pa11, o1, 0, 0, 0);
        __builtin_amdgcn_s_setprio(0);

        __syncthreads();
        cur ^= 1;
    }

    // merge the hi-half partial denominators once, normalize, write aoT
    float l = l_i + __shfl_xor(l_i, 32);
    float inv = 1.f / l;
    unsigned short* op = aoT + ((size_t)b * NN + n) * CC + h * DH;
    #pragma unroll
    for (int q = 0; q < 4; ++q) {
        ushort4 pk;
        pk.x = bfb(o0[4 * q + 0] * inv);
        pk.y = bfb(o0[4 * q + 1] * inv);
        pk.z = bfb(o0[4 * q + 2] * inv);
        pk.w = bfb(o0[4 * q + 3] * inv);
        *reinterpret_cast<ushort4*>(op + q * 8 + hi * 4) = pk;
        ushort4 pk2;
        pk2.x = bfb(o1[4 * q + 0] * inv);
        pk2.y = bfb(o1[4 * q + 1] * inv);
        pk2.z = bfb(o1[4 * q + 2] * inv);
        pk2.w = bfb(o1[4 * q + 3] * inv);
        *reinterpret_cast<ushort4*>(op + 32 + q * 8 + hi * 4) = pk2;
    }
}

// ---------------- kernel 4: output projection, LDS-staged GEMM + bias + residual ----------------
__global__ __launch_bounds__(256, 2) void oproj2_kernel(
    const unsigned short* __restrict__ wob, const float* __restrict__ bo,
    const unsigned short* __restrict__ aoT, const float* __restrict__ x,
    float* __restrict__ out) {
    int wg = blockIdx.x;
    int xcd = wg & 7, local = wg >> 3;        // local 0..63
    int mloc = local >> 2;                     // 0..15
    int n_tile = local & 3;                    // 0..3
    int m_tile = xcd * 16 + mloc;              // 0..127
    int row0 = m_tile * 128;
    int o0t = n_tile * 128;

    __shared__ __align__(16) char As[2][16384];
    __shared__ __align__(16) char Bs[2][16384];

    int t = threadIdx.x;
    int lane = t & 63, wid = t >> 6;
    int Rl = lane >> 3;
    int csw = ((lane & 7) ^ Rl) << 4;

    const char* Ag = (const char*)aoT + (size_t)row0 * 1024;
    const char* Bg = (const char*)wob + (size_t)o0t * 1024;

    #pragma unroll
    for (int j = 0; j < 4; ++j) {
        int ii = wid * 4 + j;
        size_t ro = (size_t)(ii * 8 + Rl) * 1024 + csw;
        gload_lds16(Ag + ro, &As[0][ii * 1024]);
        gload_lds16(Bg + ro, &Bs[0][ii * 1024]);
    }
    __syncthreads();

    int wr = wid & 1, wc = wid >> 1;
    int lr = lane & 15, lg = lane >> 4;
    f32x4 acc[4][4] = {};

    for (int ks = 0; ks < 8; ++ks) {
        int cb_ = ks & 1;
        if (ks < 7) {
            int k0 = (ks + 1) * 64;
            #pragma unroll
            for (int j = 0; j < 4; ++j) {
                int ii = wid * 4 + j;
                size_t ro = (size_t)(ii * 8 + Rl) * 1024 + k0 * 2 + csw;
                gload_lds16(Ag + ro, &As[cb_ ^ 1][ii * 1024]);
                gload_lds16(Bg + ro, &Bs[cb_ ^ 1][ii * 1024]);
            }
        }
        const char* al = As[cb_];
        const char* bl = Bs[cb_];
        #pragma unroll
        for (int kk = 0; kk < 2; ++kk) {
            bf16x8 wf[4], xf[4];
            #pragma unroll
            for (int r = 0; r < 4; ++r) {
                int row = wc * 64 + r * 16 + lr;
                wf[r] = ldb8(bl + row * 128 + (((kk * 4 + lg) ^ (row & 7)) << 4));
            }
            #pragma unroll
            for (int c = 0; c < 4; ++c) {
                int row = wr * 64 + c * 16 + lr;
                xf[c] = ldb8(al + row * 128 + (((kk * 4 + lg) ^ (row & 7)) << 4));
            }
            __builtin_amdgcn_s_setprio(1);
            #pragma unroll
            for (int r = 0; r < 4; ++r)
                #pragma unroll
                for (int c = 0; c < 4; ++c)
                    acc[r][c] = __builtin_amdgcn_mfma_f32_16x16x32_bf16(wf[r], xf[c], acc[r][c], 0, 0, 0);
            __builtin_amdgcn_s_setprio(0);
        }
        __syncthreads();
    }

    #pragma unroll
    for (int r = 0; r < 4; ++r) {
        int o0 = o0t + wc * 64 + r * 16 + lg * 4;
        #pragma unroll
        for (int c = 0; c < 4; ++c) {
            int grow = row0 + wr * 64 + c * 16 + lr;
            int b = grow >> 10, n = grow & 1023;
            #pragma unroll
            for (int j = 0; j < 4; ++j) {
                size_t idx = ((size_t)b * CC + o0 + j) * NN + n;
                out[idx] = acc[r][c][j] + bo[o0 + j] + x[idx];
            }
        }
    }
}

extern "C" void kernel_launch(void* const* d_in, const int* in_sizes, int n_in,
                              void* d_out, int out_size, void* d_ws, size_t ws_size,
                              hipStream_t stream) {
    const float* x     = (const float*)d_in[0];
    const float* wq    = (const float*)d_in[1];
    const float* bq    = (const float*)d_in[2];
    const float* wk    = (const float*)d_in[3];
    const float* bk    = (const float*)d_in[4];
    const float* wv    = (const float*)d_in[5];
    const float* bv    = (const float*)d_in[6];
    const float* wo    = (const float*)d_in[7];
    const float* bo    = (const float*)d_in[8];
    const float* gamma = (const float*)d_in[9];
    const float* beta  = (const float*)d_in[10];

    char* ws = (char*)d_ws;
    const size_t WSZ = (size_t)CC * CC * 2;           // 512 KB per weight
    const size_t TEN = (size_t)BB * NN * CC * 2;      // 16.78 MB per tensor
    unsigned short* wqb = (unsigned short*)(ws);
    unsigned short* wkb = (unsigned short*)(ws + WSZ);
    unsigned short* wvb = (unsigned short*)(ws + 2 * WSZ);
    unsigned short* wob = (unsigned short*)(ws + 3 * WSZ);
    unsigned short* xnT = (unsigned short*)(ws + 4 * WSZ);
    unsigned short* qt  = (unsigned short*)(ws + 4 * WSZ + TEN);
    unsigned short* kt  = (unsigned short*)(ws + 4 * WSZ + 2 * TEN);
    unsigned short* vv  = (unsigned short*)(ws + 4 * WSZ + 3 * TEN);
    unsigned short* aoT = (unsigned short*)(ws + 4 * WSZ + 4 * TEN);

    wconv_kernel<<<dim3(256), dim3(256), 0, stream>>>(
        (const float4*)wq, (const float4*)wk, (const float4*)wv, (const float4*)wo,
        (ushort4*)wqb, (ushort4*)wkb, (ushort4*)wvb, (ushort4*)wob);
    gn_kernel<<<dim3(128), dim3(1024), 0, stream>>>(x, gamma, beta, xnT);
    qkv2_kernel<<<dim3(1536), dim3(256), 0, stream>>>(
        wqb, wkb, wvb, bq, bk, bv, xnT, qt, kt, vv);
    attn4_kernel<<<dim3(1024), dim3(256), 0, stream>>>(qt, kt, vv, aoT);
    oproj2_kernel<<<dim3(512), dim3(256), 0, stream>>>(wob, bo, aoT, x, (float*)d_out);
}